// Round 2
// baseline (267.812 us; speedup 1.0000x reference)
//
#include <hip/hip_runtime.h>

typedef __bf16 bf16x8 __attribute__((ext_vector_type(8)));
typedef float f32x4 __attribute__((ext_vector_type(4)));

__device__ __forceinline__ unsigned short f2bf(float f) {
    unsigned int u = __builtin_bit_cast(unsigned int, f);
    u += 0x7fff + ((u >> 16) & 1);   // round-to-nearest-even (inputs are finite)
    return (unsigned short)(u >> 16);
}

// ---------------------------------------------------------------------------
// Transpose + fp32->bf16 convert: D[b][j][i] = bf16(S[b][i][j]), 256x256 per batch.
// grid (16 tiles, B, nz), block 256. z picks (S0,D0) vs (S1,D1).
// ---------------------------------------------------------------------------
__global__ __launch_bounds__(256)
void transpose_cvt(const float* __restrict__ S0, unsigned short* __restrict__ D0,
                   const float* __restrict__ S1, unsigned short* __restrict__ D1)
{
    const float* S = blockIdx.z ? S1 : S0;
    unsigned short* D = blockIdx.z ? D1 : D0;
    const int b = blockIdx.y;
    const int t = blockIdx.x;
    const int r0 = (t >> 2) * 64;
    const int c0 = (t & 3) * 64;
    S += (long)b * 65536;
    D += (long)b * 65536;

    __shared__ float tile[64][65];
    const int tid = threadIdx.x;

    // load 64x64 fp32 tile: 256 thr x 4 floats x 4 iters
#pragma unroll
    for (int it = 0; it < 4; ++it) {
        int r = it * 16 + (tid >> 4);       // 0..63
        int c = (tid & 15) * 4;             // 0..60
        float4 v = *(const float4*)&S[(long)(r0 + r) * 256 + c0 + c];
        tile[r][c + 0] = v.x; tile[r][c + 1] = v.y;
        tile[r][c + 2] = v.z; tile[r][c + 3] = v.w;
    }
    __syncthreads();
    // store transposed as bf16: 256 thr x 16 iters
#pragma unroll
    for (int it = 0; it < 16; ++it) {
        int rr = it * 4 + (tid >> 6);   // output row (j) 0..63
        int cc = tid & 63;              // output col (i) 0..63
        D[(long)(c0 + rr) * 256 + r0 + cc] = f2bf(tile[cc][rr]);
    }
}

// ---------------------------------------------------------------------------
// Build Wcat[g][q][512] = [W_gx | W_gh] rows (bf16) and Woc bf16.
// ---------------------------------------------------------------------------
__global__ __launch_bounds__(256)
void cvt_weights(const float* __restrict__ fx, const float* __restrict__ ix,
                 const float* __restrict__ ox, const float* __restrict__ gx,
                 const float* __restrict__ fh, const float* __restrict__ ih,
                 const float* __restrict__ oh, const float* __restrict__ gh,
                 const float* __restrict__ oc,
                 unsigned short* __restrict__ Wcat, unsigned short* __restrict__ Wocb)
{
    int idx = blockIdx.x * 256 + threadIdx.x;
    if (idx < 524288) {
        int g = idx >> 17;
        int rem = idx & 131071;
        int q = rem >> 9;
        int j = rem & 511;
        const float* xs = (g == 0) ? fx : (g == 1) ? ix : (g == 2) ? ox : gx;
        const float* hs = (g == 0) ? fh : (g == 1) ? ih : (g == 2) ? oh : gh;
        float v = (j < 256) ? xs[q * 256 + j] : hs[q * 256 + (j - 256)];
        Wcat[idx] = f2bf(v);
    } else if (idx < 589824) {
        int k = idx - 524288;
        Wocb[k] = f2bf(oc[k]);
    }
}

// ---------------------------------------------------------------------------
// NT GEMM: C[m,n] = op( sum_k A[m,k] * B[n,k] )   M=N=256, K param (mult of 64)
// 128x128 tile per block (blockIdx.x in 0..3), 4 waves of 64x64, 16x16x32 MFMA.
// MODE 0: bf16 store raw sum
// MODE 1: f32 store relu(sum) + addp[idx]
// MODE 2: f32 C[idx] += relu(sum)
// MODE 4: f32 store relu(sum)
// ---------------------------------------------------------------------------
template <int MODE>
__global__ __launch_bounds__(256)
void gemm_nt(const unsigned short* __restrict__ A, int lda, long sAy, long sAz,
             const unsigned short* __restrict__ B0, const unsigned short* __restrict__ B1,
             int ldb, long sBy,
             void* __restrict__ Cv, int ldc, long sCy, long sCz,
             const float* __restrict__ addp, long sAddY, int K)
{
    __shared__ alignas(16) unsigned short Alds[128 * 64];
    __shared__ alignas(16) unsigned short Blds[128 * 64];

    const int tid = threadIdx.x;
    const int lane = tid & 63;
    const int w = tid >> 6;
    const int tm = (blockIdx.x >> 1) * 128;
    const int tn = (blockIdx.x & 1) * 128;

    const unsigned short* Ap = A + blockIdx.y * sAy + blockIdx.z * sAz + (long)tm * lda;
    const unsigned short* Bp = ((blockIdx.z & 1) ? B1 : B0) + blockIdx.y * sBy + (long)tn * ldb;

    const int wm = (w >> 1) * 64;
    const int wn = (w & 1) * 64;

    f32x4 acc[4][4];
#pragma unroll
    for (int m = 0; m < 4; ++m)
#pragma unroll
        for (int n = 0; n < 4; ++n)
            acc[m][n] = (f32x4){0.f, 0.f, 0.f, 0.f};

    for (int k0 = 0; k0 < K; k0 += 64) {
#pragma unroll
        for (int it = 0; it < 4; ++it) {
            int li = it * 256 + tid;       // 0..1023 : row = li>>3, 16B chunk = li&7
            int row = li >> 3;
            int ck = (li & 7) * 8;
            const unsigned short* ga = Ap + (long)row * lda + k0 + ck;
            const unsigned short* gb = Bp + (long)row * ldb + k0 + ck;
            __builtin_amdgcn_global_load_lds(
                (const __attribute__((address_space(1))) void*)ga,
                (__attribute__((address_space(3))) void*)&Alds[li * 8], 16, 0, 0);
            __builtin_amdgcn_global_load_lds(
                (const __attribute__((address_space(1))) void*)gb,
                (__attribute__((address_space(3))) void*)&Blds[li * 8], 16, 0, 0);
        }
        __syncthreads();
#pragma unroll
        for (int kk = 0; kk < 2; ++kk) {
            const int ko = kk * 32 + (lane >> 4) * 8;
            bf16x8 af[4], bfr[4];
#pragma unroll
            for (int m = 0; m < 4; ++m)
                af[m] = *(const bf16x8*)&Alds[(wm + m * 16 + (lane & 15)) * 64 + ko];
#pragma unroll
            for (int n = 0; n < 4; ++n)
                bfr[n] = *(const bf16x8*)&Blds[(wn + n * 16 + (lane & 15)) * 64 + ko];
#pragma unroll
            for (int m = 0; m < 4; ++m)
#pragma unroll
                for (int n = 0; n < 4; ++n)
                    acc[m][n] = __builtin_amdgcn_mfma_f32_16x16x32_bf16(af[m], bfr[n], acc[m][n], 0, 0, 0);
        }
        __syncthreads();
    }

    const long coff = blockIdx.y * sCy + blockIdx.z * sCz;
    const int r0 = (lane >> 4) * 4;
    const int c0 = lane & 15;

    if (MODE == 0) {
        unsigned short* C = (unsigned short*)Cv + coff;
#pragma unroll
        for (int m = 0; m < 4; ++m)
#pragma unroll
            for (int n = 0; n < 4; ++n)
#pragma unroll
                for (int r = 0; r < 4; ++r) {
                    int row = tm + wm + m * 16 + r0 + r;
                    int col = tn + wn + n * 16 + c0;
                    C[(long)row * ldc + col] = f2bf(acc[m][n][r]);
                }
    } else {
        float* C = (float*)Cv + coff;
        const float* addb = addp + blockIdx.y * sAddY;
#pragma unroll
        for (int m = 0; m < 4; ++m)
#pragma unroll
            for (int n = 0; n < 4; ++n)
#pragma unroll
                for (int r = 0; r < 4; ++r) {
                    int row = tm + wm + m * 16 + r0 + r;
                    int col = tn + wn + n * 16 + c0;
                    long idx = (long)row * ldc + col;
                    float v = acc[m][n][r];
                    v = v > 0.f ? v : 0.f;
                    if (MODE == 1) C[idx] = v + addb[idx];
                    else if (MODE == 2) C[idx] += v;
                    else C[idx] = v;
                }
    }
}

// ---------------------------------------------------------------------------
extern "C" void kernel_launch(void* const* d_in, const int* in_sizes, int n_in,
                              void* d_out, int out_size, void* d_ws, size_t ws_size,
                              hipStream_t stream)
{
    (void)in_sizes; (void)n_in; (void)out_size; (void)ws_size;

    const float* X    = (const float*)d_in[0];
    const float* H    = (const float*)d_in[1];
    const float* cell = (const float*)d_in[2];
    const float* Wxp[4] = {(const float*)d_in[3], (const float*)d_in[4],
                           (const float*)d_in[5], (const float*)d_in[6]};
    const float* Whp[4] = {(const float*)d_in[7], (const float*)d_in[8],
                           (const float*)d_in[9], (const float*)d_in[10]};
    const float* Wocf = (const float*)d_in[11];

    float* out_h = (float*)d_out;                  // [128][256][256]
    float* out_c = out_h + 8388608;                // [128][256][256]

    unsigned short* ws   = (unsigned short*)d_ws;  // bf16 elements
    unsigned short* XbT  = ws;                     //  8,388,608 el (X^T bf16)
    unsigned short* HbT  = ws + 8388608;           //  8,388,608 el (H^T bf16)
    unsigned short* Wcat = ws + 16777216;          //    524,288 el [4][256][512]
    unsigned short* Wocb = ws + 17301504;          //     65,536 el [256][256]
    unsigned short* Tcat = ws + 17367040;          // 16,777,216 el [128][256][512]
    unsigned short* CbT  = XbT;                    // reuse after gates done
    unsigned short* U    = HbT;                    // reuse after gates done

    // 1. X^T, H^T -> bf16
    transpose_cvt<<<dim3(16, 128, 2), 256, 0, stream>>>(X, XbT, H, HbT);
    // 2. weights -> bf16 (concatenated [Wx|Wh] per gate)
    cvt_weights<<<dim3(2304), 256, 0, stream>>>(Wxp[0], Wxp[1], Wxp[2], Wxp[3],
                                                Whp[0], Whp[1], Whp[2], Whp[3],
                                                Wocf, Wcat, Wocb);

    // 3. per gate g (0=f,1=i,2=o,3=g):
    for (int g = 0; g < 4; ++g) {
        const unsigned short* Wg = Wcat + (long)g * 131072;
        // stage A: Tcat[b][o][half*256+j] = sum_i W_half[o,i] * M_half^T[b][j][i]
        gemm_nt<0><<<dim3(4, 128, 2), 256, 0, stream>>>(
            Wg, 512, 0L, 256L,
            XbT, HbT, 256, 65536L,
            (void*)Tcat, 512, 131072L, 256L,
            nullptr, 0L, 256);
        // stage B: gate[b][o][q] = relu( sum_{j'} Tcat[b][o][j'] * Wcat_g[q][j'] ), K=512
        if (g == 0) {
            gemm_nt<1><<<dim3(4, 128, 1), 256, 0, stream>>>(
                Tcat, 512, 131072L, 0L, Wg, Wg, 512, 0L,
                (void*)out_c, 256, 65536L, 0L, cell, 65536L, 512);
        } else if (g == 2) {
            gemm_nt<4><<<dim3(4, 128, 1), 256, 0, stream>>>(
                Tcat, 512, 131072L, 0L, Wg, Wg, 512, 0L,
                (void*)out_h, 256, 65536L, 0L, out_h /*unused*/, 0L, 512);
        } else {
            gemm_nt<2><<<dim3(4, 128, 1), 256, 0, stream>>>(
                Tcat, 512, 131072L, 0L, Wg, Wg, 512, 0L,
                (void*)out_c, 256, 65536L, 0L, out_c /*unused*/, 0L, 512);
        }
    }

    // 4. c -> c^T bf16
    transpose_cvt<<<dim3(16, 128, 1), 256, 0, stream>>>(out_c, CbT, out_c, CbT);

    // 5. U[b][o][j] = sum_i Woc[o,i] * c^T[b][j][i]
    gemm_nt<0><<<dim3(4, 128, 1), 256, 0, stream>>>(
        Wocb, 256, 0L, 0L, CbT, CbT, 256, 65536L,
        (void*)U, 256, 65536L, 0L, nullptr, 0L, 256);

    // 6. h[b][o][q] = ogate[b][o][q] (already in out_h) + relu( sum_j U[b,o,j] Woc[q,j] )
    gemm_nt<2><<<dim3(4, 128, 1), 256, 0, stream>>>(
        U, 256, 65536L, 0L, Wocb, Wocb, 256, 0L,
        (void*)out_h, 256, 65536L, 0L, out_h /*unused*/, 0L, 256);
}

// Round 3
// 232.244 us; speedup vs baseline: 1.1532x; 1.1532x over previous
//
#include <hip/hip_runtime.h>

typedef __bf16 bf16x8 __attribute__((ext_vector_type(8)));
typedef float f32x4 __attribute__((ext_vector_type(4)));

__device__ __forceinline__ unsigned short f2bf(float f) {
    unsigned int u = __builtin_bit_cast(unsigned int, f);
    u += 0x7fff + ((u >> 16) & 1);   // round-to-nearest-even (finite inputs)
    return (unsigned short)(u >> 16);
}

// ---------------------------------------------------------------------------
// Shared 128x128-tile NT K-loop: acc += A[128][K] * B[128][K]^T (bf16, MFMA).
// Alds/Blds are 128*64-element staging buffers. Trailing __syncthreads().
// ---------------------------------------------------------------------------
__device__ __forceinline__ void kloop(
    const unsigned short* __restrict__ Ap, int lda,
    const unsigned short* __restrict__ Bp, int ldb,
    unsigned short* Alds, unsigned short* Blds,
    int K, int tid, int lane, int wm, int wn, f32x4 (&acc)[4][4])
{
    for (int k0 = 0; k0 < K; k0 += 64) {
#pragma unroll
        for (int it = 0; it < 4; ++it) {
            int li = it * 256 + tid;       // 0..1023 : row = li>>3, 16B chunk = li&7
            int row = li >> 3;
            int ck = (li & 7) * 8;
            __builtin_amdgcn_global_load_lds(
                (const __attribute__((address_space(1))) void*)(Ap + (long)row * lda + k0 + ck),
                (__attribute__((address_space(3))) void*)&Alds[li * 8], 16, 0, 0);
            __builtin_amdgcn_global_load_lds(
                (const __attribute__((address_space(1))) void*)(Bp + (long)row * ldb + k0 + ck),
                (__attribute__((address_space(3))) void*)&Blds[li * 8], 16, 0, 0);
        }
        __syncthreads();
#pragma unroll
        for (int kk = 0; kk < 2; ++kk) {
            const int ko = kk * 32 + (lane >> 4) * 8;
            bf16x8 af[4], bfr[4];
#pragma unroll
            for (int m = 0; m < 4; ++m)
                af[m] = *(const bf16x8*)&Alds[(wm + m * 16 + (lane & 15)) * 64 + ko];
#pragma unroll
            for (int n = 0; n < 4; ++n)
                bfr[n] = *(const bf16x8*)&Blds[(wn + n * 16 + (lane & 15)) * 64 + ko];
#pragma unroll
            for (int m = 0; m < 4; ++m)
#pragma unroll
                for (int n = 0; n < 4; ++n)
                    acc[m][n] = __builtin_amdgcn_mfma_f32_16x16x32_bf16(af[m], bfr[n], acc[m][n], 0, 0, 0);
        }
        __syncthreads();
    }
}

// ---------------------------------------------------------------------------
// Transpose + fp32->bf16: D[b][j][i] = bf16(S[b][i][j]), 256x256 per batch.
// ---------------------------------------------------------------------------
__global__ __launch_bounds__(256)
void transpose_cvt(const float* __restrict__ S0, unsigned short* __restrict__ D0,
                   const float* __restrict__ S1, unsigned short* __restrict__ D1)
{
    const float* S = blockIdx.z ? S1 : S0;
    unsigned short* D = blockIdx.z ? D1 : D0;
    const int b = blockIdx.y;
    const int t = blockIdx.x;
    const int r0 = (t >> 2) * 64;
    const int c0 = (t & 3) * 64;
    S += (long)b * 65536;
    D += (long)b * 65536;

    __shared__ float tile[64][65];
    const int tid = threadIdx.x;

#pragma unroll
    for (int it = 0; it < 4; ++it) {
        int r = it * 16 + (tid >> 4);
        int c = (tid & 15) * 4;
        float4 v = *(const float4*)&S[(long)(r0 + r) * 256 + c0 + c];
        tile[r][c + 0] = v.x; tile[r][c + 1] = v.y;
        tile[r][c + 2] = v.z; tile[r][c + 3] = v.w;
    }
    __syncthreads();
#pragma unroll
    for (int it = 0; it < 16; ++it) {
        int rr = it * 4 + (tid >> 6);
        int cc = tid & 63;
        D[(long)(c0 + rr) * 256 + r0 + cc] = f2bf(tile[cc][rr]);
    }
}

// ---------------------------------------------------------------------------
// Build Wcat[g][q][512] = [W_gx | W_gh] rows (bf16) and Woc bf16.
// ---------------------------------------------------------------------------
__global__ __launch_bounds__(256)
void cvt_weights(const float* __restrict__ fx, const float* __restrict__ ix,
                 const float* __restrict__ ox, const float* __restrict__ gx,
                 const float* __restrict__ fh, const float* __restrict__ ih,
                 const float* __restrict__ oh, const float* __restrict__ gh,
                 const float* __restrict__ oc,
                 unsigned short* __restrict__ Wcat, unsigned short* __restrict__ Wocb)
{
    int idx = blockIdx.x * 256 + threadIdx.x;
    if (idx < 524288) {
        int g = idx >> 17;
        int rem = idx & 131071;
        int q = rem >> 9;
        int j = rem & 511;
        const float* xs = (g == 0) ? fx : (g == 1) ? ix : (g == 2) ? ox : gx;
        const float* hs = (g == 0) ? fh : (g == 1) ? ih : (g == 2) ? oh : gh;
        float v = (j < 256) ? xs[q * 256 + j] : hs[q * 256 + (j - 256)];
        Wcat[idx] = f2bf(v);
    } else if (idx < 589824) {
        int k = idx - 524288;
        Wocb[k] = f2bf(oc[k]);
    }
}

// ---------------------------------------------------------------------------
// Stage A, all gates: Tcat[g][b][o][hf*256+j] = sum_i Whalf[o,i]*Mhalf^T[b][j][i]
// grid (4, 128, 8): z = gate*2 + half
// ---------------------------------------------------------------------------
__global__ __launch_bounds__(256)
void gemm_stageA(const unsigned short* __restrict__ Wcat,
                 const unsigned short* __restrict__ XbT,
                 const unsigned short* __restrict__ HbT,
                 unsigned short* __restrict__ Tcat)
{
    __shared__ alignas(16) unsigned short Alds[8192];
    __shared__ alignas(16) unsigned short Blds[8192];

    const int tid = threadIdx.x;
    const int lane = tid & 63;
    const int w = tid >> 6;
    const int tm = (blockIdx.x >> 1) * 128;
    const int tn = (blockIdx.x & 1) * 128;
    const int b = blockIdx.y;
    const int g = blockIdx.z >> 1;
    const int hf = blockIdx.z & 1;
    const int wm = (w >> 1) * 64;
    const int wn = (w & 1) * 64;

    const unsigned short* Ap = Wcat + (long)g * 131072 + hf * 256 + (long)tm * 512;
    const unsigned short* Bp = (hf ? HbT : XbT) + (long)b * 65536 + (long)tn * 256;

    f32x4 acc[4][4];
#pragma unroll
    for (int m = 0; m < 4; ++m)
#pragma unroll
        for (int n = 0; n < 4; ++n)
            acc[m][n] = (f32x4){0.f, 0.f, 0.f, 0.f};

    kloop(Ap, 512, Bp, 256, Alds, Blds, 256, tid, lane, wm, wn, acc);

    unsigned short* C = Tcat + (long)g * 16777216 + (long)b * 131072 + hf * 256;
    const int r0 = (lane >> 4) * 4;
    const int c0 = lane & 15;
#pragma unroll
    for (int m = 0; m < 4; ++m)
#pragma unroll
        for (int n = 0; n < 4; ++n)
#pragma unroll
            for (int r = 0; r < 4; ++r) {
                int row = tm + wm + m * 16 + r0 + r;
                int col = tn + wn + n * 16 + c0;
                C[(long)row * 512 + col] = f2bf(acc[m][n][r]);
            }
}

// ---------------------------------------------------------------------------
// Fused c-gate stage B: c = cell + relu(f) + relu(i) + relu(g), writes fp32
// out_c AND bf16 transposed CbT[b][j][i]. grid (4, 128).
// ---------------------------------------------------------------------------
__global__ __launch_bounds__(256)
void gemm_fused_c(const unsigned short* __restrict__ Tcat,
                  const unsigned short* __restrict__ Wcat,
                  const float* __restrict__ cell,
                  float* __restrict__ out_c,
                  unsigned short* __restrict__ CbT)
{
    __shared__ alignas(16) unsigned short smem[17408];  // staging 16384 | transpose 128*136
    unsigned short* Alds = smem;
    unsigned short* Blds = smem + 8192;

    const int tid = threadIdx.x;
    const int lane = tid & 63;
    const int w = tid >> 6;
    const int tm = (blockIdx.x >> 1) * 128;
    const int tn = (blockIdx.x & 1) * 128;
    const int b = blockIdx.y;
    const int wm = (w >> 1) * 64;
    const int wn = (w & 1) * 64;

    f32x4 accc[4][4];
#pragma unroll
    for (int m = 0; m < 4; ++m)
#pragma unroll
        for (int n = 0; n < 4; ++n)
            accc[m][n] = (f32x4){0.f, 0.f, 0.f, 0.f};

    const int glist[3] = {0, 1, 3};
#pragma unroll
    for (int gi = 0; gi < 3; ++gi) {
        const int g = glist[gi];
        f32x4 acc[4][4];
#pragma unroll
        for (int m = 0; m < 4; ++m)
#pragma unroll
            for (int n = 0; n < 4; ++n)
                acc[m][n] = (f32x4){0.f, 0.f, 0.f, 0.f};
        const unsigned short* Ap = Tcat + (long)g * 16777216 + (long)b * 131072 + (long)tm * 512;
        const unsigned short* Bp = Wcat + (long)g * 131072 + (long)tn * 512;
        kloop(Ap, 512, Bp, 512, Alds, Blds, 512, tid, lane, wm, wn, acc);
#pragma unroll
        for (int m = 0; m < 4; ++m)
#pragma unroll
            for (int n = 0; n < 4; ++n)
#pragma unroll
                for (int r = 0; r < 4; ++r) {
                    float v = acc[m][n][r];
                    accc[m][n][r] += (v > 0.f ? v : 0.f);
                }
    }

    // epilogue: add cell, write out_c fp32, stash transposed bf16 tile in LDS
    unsigned short (*ldsT)[136] = (unsigned short(*)[136])smem;
    const float* cb = cell + (long)b * 65536;
    float* co = out_c + (long)b * 65536;
    const int r0 = (lane >> 4) * 4;
    const int c0 = lane & 15;
#pragma unroll
    for (int m = 0; m < 4; ++m)
#pragma unroll
        for (int n = 0; n < 4; ++n)
#pragma unroll
            for (int r = 0; r < 4; ++r) {
                int row = wm + m * 16 + r0 + r;   // local 0..127
                int col = wn + n * 16 + c0;       // local 0..127
                float v = accc[m][n][r] + cb[(long)(tm + row) * 256 + tn + col];
                co[(long)(tm + row) * 256 + tn + col] = v;
                ldsT[col][row] = f2bf(v);
            }
    __syncthreads();
    unsigned short* cbt = CbT + (long)b * 65536;
#pragma unroll
    for (int it = 0; it < 8; ++it) {
        int idx = it * 256 + tid;      // 0..2047
        int jj = idx >> 4;             // 0..127 (local j = col)
        int ch = idx & 15;             // 16 chunks of 8 elements
        uint4 v = *(const uint4*)&ldsT[jj][ch * 8];
        *(uint4*)&cbt[(long)(tn + jj) * 256 + tm + ch * 8] = v;
    }
}

// ---------------------------------------------------------------------------
// Generic NT GEMM (M=N=256 per batch): MODE 0 bf16 raw, MODE 2 f32 +=relu,
// MODE 4 f32 relu.
// ---------------------------------------------------------------------------
template <int MODE>
__global__ __launch_bounds__(256)
void gemm_nt(const unsigned short* __restrict__ A, int lda, long sAy,
             const unsigned short* __restrict__ B, int ldb, long sBy,
             void* __restrict__ Cv, int ldc, long sCy, int K)
{
    __shared__ alignas(16) unsigned short Alds[8192];
    __shared__ alignas(16) unsigned short Blds[8192];

    const int tid = threadIdx.x;
    const int lane = tid & 63;
    const int w = tid >> 6;
    const int tm = (blockIdx.x >> 1) * 128;
    const int tn = (blockIdx.x & 1) * 128;
    const int wm = (w >> 1) * 64;
    const int wn = (w & 1) * 64;

    const unsigned short* Ap = A + blockIdx.y * sAy + (long)tm * lda;
    const unsigned short* Bp = B + blockIdx.y * sBy + (long)tn * ldb;

    f32x4 acc[4][4];
#pragma unroll
    for (int m = 0; m < 4; ++m)
#pragma unroll
        for (int n = 0; n < 4; ++n)
            acc[m][n] = (f32x4){0.f, 0.f, 0.f, 0.f};

    kloop(Ap, lda, Bp, ldb, Alds, Blds, K, tid, lane, wm, wn, acc);

    const long coff = blockIdx.y * sCy;
    const int r0 = (lane >> 4) * 4;
    const int c0 = lane & 15;

    if (MODE == 0) {
        unsigned short* C = (unsigned short*)Cv + coff;
#pragma unroll
        for (int m = 0; m < 4; ++m)
#pragma unroll
            for (int n = 0; n < 4; ++n)
#pragma unroll
                for (int r = 0; r < 4; ++r) {
                    int row = tm + wm + m * 16 + r0 + r;
                    int col = tn + wn + n * 16 + c0;
                    C[(long)row * ldc + col] = f2bf(acc[m][n][r]);
                }
    } else {
        float* C = (float*)Cv + coff;
#pragma unroll
        for (int m = 0; m < 4; ++m)
#pragma unroll
            for (int n = 0; n < 4; ++n)
#pragma unroll
                for (int r = 0; r < 4; ++r) {
                    int row = tm + wm + m * 16 + r0 + r;
                    int col = tn + wn + n * 16 + c0;
                    long idx = (long)row * ldc + col;
                    float v = acc[m][n][r];
                    v = v > 0.f ? v : 0.f;
                    if (MODE == 2) C[idx] += v;
                    else C[idx] = v;
                }
    }
}

// ---------------------------------------------------------------------------
extern "C" void kernel_launch(void* const* d_in, const int* in_sizes, int n_in,
                              void* d_out, int out_size, void* d_ws, size_t ws_size,
                              hipStream_t stream)
{
    (void)in_sizes; (void)n_in; (void)out_size; (void)ws_size;

    const float* X    = (const float*)d_in[0];
    const float* H    = (const float*)d_in[1];
    const float* cell = (const float*)d_in[2];
    const float* Wxp[4] = {(const float*)d_in[3], (const float*)d_in[4],
                           (const float*)d_in[5], (const float*)d_in[6]};
    const float* Whp[4] = {(const float*)d_in[7], (const float*)d_in[8],
                           (const float*)d_in[9], (const float*)d_in[10]};
    const float* Wocf = (const float*)d_in[11];

    float* out_h = (float*)d_out;                  // [128][256][256]
    float* out_c = out_h + 8388608;                // [128][256][256]

    unsigned short* ws   = (unsigned short*)d_ws;  // bf16 elements (ws = 256 MiB)
    unsigned short* XbT  = ws;                     //  8,388,608 el
    unsigned short* HbT  = ws + 8388608;           //  8,388,608 el
    unsigned short* Wcat = ws + 16777216;          //    524,288 el [4][256][512]
    unsigned short* Wocb = ws + 17301504;          //     65,536 el
    unsigned short* Tcat = ws + 17367040;          // 67,108,864 el [4][128][256][512]
    unsigned short* CbT  = XbT;                    // reuse (dead after stage A)
    unsigned short* U    = HbT;                    // reuse (dead after stage A)

    // 1. X^T, H^T -> bf16
    transpose_cvt<<<dim3(16, 128, 2), 256, 0, stream>>>(X, XbT, H, HbT);
    // 2. weights -> bf16
    cvt_weights<<<dim3(2304), 256, 0, stream>>>(Wxp[0], Wxp[1], Wxp[2], Wxp[3],
                                                Whp[0], Whp[1], Whp[2], Whp[3],
                                                Wocf, Wcat, Wocb);
    // 3. stage A for all 4 gates
    gemm_stageA<<<dim3(4, 128, 8), 256, 0, stream>>>(Wcat, XbT, HbT, Tcat);
    // 4. fused c = cell + relu(f)+relu(i)+relu(g); writes out_c + CbT (bf16 ^T)
    gemm_fused_c<<<dim3(4, 128), 256, 0, stream>>>(Tcat, Wcat, cell, out_c, CbT);
    // 5. o-gate: out_h = relu(T_o . Wcat_o^T)
    gemm_nt<4><<<dim3(4, 128), 256, 0, stream>>>(
        Tcat + 2L * 16777216, 512, 131072L, Wcat + 2L * 131072, 512, 0L,
        (void*)out_h, 256, 65536L, 512);
    // 6. U[b][o][j] = sum_i Woc[o,i] * c^T[b][j][i]   (bf16 out)
    gemm_nt<0><<<dim3(4, 128), 256, 0, stream>>>(
        Wocb, 256, 0L, CbT, 256, 65536L,
        (void*)U, 256, 65536L, 256);
    // 7. h = ogate + relu(U . Woc^T)   (fp32 RMW on out_h)
    gemm_nt<2><<<dim3(4, 128), 256, 0, stream>>>(
        U, 256, 65536L, Wocb, 256, 0L,
        (void*)out_h, 256, 65536L, 256);
}

// Round 4
// 194.438 us; speedup vs baseline: 1.3774x; 1.1944x over previous
//
#include <hip/hip_runtime.h>

typedef __bf16 bf16x8 __attribute__((ext_vector_type(8)));
typedef float f32x4 __attribute__((ext_vector_type(4)));

__device__ __forceinline__ unsigned short f2bf(float f) {
    unsigned int u = __builtin_bit_cast(unsigned int, f);
    u += 0x7fff + ((u >> 16) & 1);   // round-to-nearest-even (finite inputs)
    return (unsigned short)(u >> 16);
}

// ---------------------------------------------------------------------------
// Stage one 128x64 A-tile + 128x64 B-tile into LDS (linear dest, source
// pre-swizzled: 16B chunk c of row r holds logical chunk c^(r&7) -> the read
// side applies the same XOR; both-sides-or-neither, rule #21).
// lds layout: [0..8191]=A, [8192..16383]=B (elements).
// ---------------------------------------------------------------------------
__device__ __forceinline__ void stage_tile(
    const unsigned short* __restrict__ Ap, int lda,
    const unsigned short* __restrict__ Bp, int ldb,
    unsigned short* lds, int k0, int tid)
{
#pragma unroll
    for (int it = 0; it < 4; ++it) {
        int li = it * 256 + tid;          // 0..1023: row = li>>3, chunk = li&7
        int row = li >> 3;
        int sc = ((li & 7) ^ (row & 7)) * 8;
        __builtin_amdgcn_global_load_lds(
            (const __attribute__((address_space(1))) void*)(Ap + (long)row * lda + k0 + sc),
            (__attribute__((address_space(3))) void*)&lds[li * 8], 16, 0, 0);
        __builtin_amdgcn_global_load_lds(
            (const __attribute__((address_space(1))) void*)(Bp + (long)row * ldb + k0 + sc),
            (__attribute__((address_space(3))) void*)&lds[8192 + li * 8], 16, 0, 0);
    }
}

// ---------------------------------------------------------------------------
// Compute one 64-deep K-step from a staged tile pair (swizzled read).
// ---------------------------------------------------------------------------
__device__ __forceinline__ void compute_tile(
    const unsigned short* lds, int lane, int wm, int wn, f32x4 (&acc)[4][4])
{
#pragma unroll
    for (int kk = 0; kk < 2; ++kk) {
        const int cl = kk * 4 + (lane >> 4);
        bf16x8 af[4], bfr[4];
#pragma unroll
        for (int m = 0; m < 4; ++m) {
            int row = wm + m * 16 + (lane & 15);
            af[m] = *(const bf16x8*)&lds[row * 64 + ((cl ^ (row & 7)) * 8)];
        }
#pragma unroll
        for (int n = 0; n < 4; ++n) {
            int row = wn + n * 16 + (lane & 15);
            bfr[n] = *(const bf16x8*)&lds[8192 + row * 64 + ((cl ^ (row & 7)) * 8)];
        }
#pragma unroll
        for (int m = 0; m < 4; ++m)
#pragma unroll
            for (int n = 0; n < 4; ++n)
                acc[m][n] = __builtin_amdgcn_mfma_f32_16x16x32_bf16(af[m], bfr[n], acc[m][n], 0, 0, 0);
    }
}

// ---------------------------------------------------------------------------
// Transpose + fp32->bf16: D[b][j][i] = bf16(S[b][i][j]), 256x256 per batch.
// ---------------------------------------------------------------------------
__global__ __launch_bounds__(256)
void transpose_cvt(const float* __restrict__ S0, unsigned short* __restrict__ D0,
                   const float* __restrict__ S1, unsigned short* __restrict__ D1)
{
    const float* S = blockIdx.z ? S1 : S0;
    unsigned short* D = blockIdx.z ? D1 : D0;
    const int b = blockIdx.y;
    const int t = blockIdx.x;
    const int r0 = (t >> 2) * 64;
    const int c0 = (t & 3) * 64;
    S += (long)b * 65536;
    D += (long)b * 65536;

    __shared__ float tile[64][65];
    const int tid = threadIdx.x;

#pragma unroll
    for (int it = 0; it < 4; ++it) {
        int r = it * 16 + (tid >> 4);
        int c = (tid & 15) * 4;
        float4 v = *(const float4*)&S[(long)(r0 + r) * 256 + c0 + c];
        tile[r][c + 0] = v.x; tile[r][c + 1] = v.y;
        tile[r][c + 2] = v.z; tile[r][c + 3] = v.w;
    }
    __syncthreads();
#pragma unroll
    for (int it = 0; it < 16; ++it) {
        int rr = it * 4 + (tid >> 6);
        int cc = tid & 63;
        D[(long)(c0 + rr) * 256 + r0 + cc] = f2bf(tile[cc][rr]);
    }
}

// ---------------------------------------------------------------------------
// Build Wcat[g][q][512] = [W_gx | W_gh] rows (bf16) and Woc bf16.
// ---------------------------------------------------------------------------
__global__ __launch_bounds__(256)
void cvt_weights(const float* __restrict__ fx, const float* __restrict__ ix,
                 const float* __restrict__ ox, const float* __restrict__ gx,
                 const float* __restrict__ fh, const float* __restrict__ ih,
                 const float* __restrict__ oh, const float* __restrict__ gh,
                 const float* __restrict__ oc,
                 unsigned short* __restrict__ Wcat, unsigned short* __restrict__ Wocb)
{
    int idx = blockIdx.x * 256 + threadIdx.x;
    if (idx < 524288) {
        int g = idx >> 17;
        int rem = idx & 131071;
        int q = rem >> 9;
        int j = rem & 511;
        const float* xs = (g == 0) ? fx : (g == 1) ? ix : (g == 2) ? ox : gx;
        const float* hs = (g == 0) ? fh : (g == 1) ? ih : (g == 2) ? oh : gh;
        float v = (j < 256) ? xs[q * 256 + j] : hs[q * 256 + (j - 256)];
        Wcat[idx] = f2bf(v);
    } else if (idx < 589824) {
        int k = idx - 524288;
        Wocb[k] = f2bf(oc[k]);
    }
}

// ---------------------------------------------------------------------------
// Stage A, all gates: Tcat[g][b][o][hf*256+j] = sum_i Whalf[o,i]*Mhalf^T[b][j][i]
// grid (4, 128, 8); XCD chunk swizzle over the 4096-block grid.
// ---------------------------------------------------------------------------
__global__ __launch_bounds__(256)
void gemm_stageA(const unsigned short* __restrict__ Wcat,
                 const unsigned short* __restrict__ XbT,
                 const unsigned short* __restrict__ HbT,
                 unsigned short* __restrict__ Tcat)
{
    __shared__ alignas(16) unsigned short lds[32768];   // 2 x (A8192|B8192)

    const int tid = threadIdx.x;
    const int lane = tid & 63;
    const int w = tid >> 6;

    int d = blockIdx.x + 4 * blockIdx.y + 512 * blockIdx.z;  // 0..4095
    int swz = (d & 7) * 512 + (d >> 3);                      // bijective (4096%8==0)
    const int x = swz & 3;
    const int b = (swz >> 2) & 127;
    const int gz = swz >> 9;          // 0..7
    const int g = gz >> 1, hf = gz & 1;
    const int tm = (x >> 1) * 128;
    const int tn = (x & 1) * 128;
    const int wm = (w >> 1) * 64;
    const int wn = (w & 1) * 64;

    const unsigned short* Ap = Wcat + (long)g * 131072 + hf * 256 + (long)tm * 512;
    const unsigned short* Bp = (hf ? HbT : XbT) + (long)b * 65536 + (long)tn * 256;

    f32x4 acc[4][4];
#pragma unroll
    for (int m = 0; m < 4; ++m)
#pragma unroll
        for (int n = 0; n < 4; ++n)
            acc[m][n] = (f32x4){0.f, 0.f, 0.f, 0.f};

    stage_tile(Ap, 512, Bp, 256, lds, 0, tid);
    __syncthreads();
    int cur = 0;
    for (int t = 0; t < 4; ++t) {
        if (t + 1 < 4)
            stage_tile(Ap, 512, Bp, 256, lds + (cur ^ 1) * 16384, (t + 1) * 64, tid);
        compute_tile(lds + cur * 16384, lane, wm, wn, acc);
        __syncthreads();
        cur ^= 1;
    }

    unsigned short* C = Tcat + (long)g * 16777216 + (long)b * 131072 + hf * 256;
    const int r0 = (lane >> 4) * 4;
    const int c0 = lane & 15;
#pragma unroll
    for (int m = 0; m < 4; ++m)
#pragma unroll
        for (int n = 0; n < 4; ++n)
#pragma unroll
            for (int r = 0; r < 4; ++r) {
                int row = tm + wm + m * 16 + r0 + r;
                int col = tn + wn + n * 16 + c0;
                C[(long)row * 512 + col] = f2bf(acc[m][n][r]);
            }
}

// ---------------------------------------------------------------------------
// Stage B, fused: z==0 -> c = cell + relu(f)+relu(i)+relu(g) (writes fp32
// out_c + bf16 transposed CbT); z==1 -> out_h = relu(o). Pipeline runs
// across gate segments (prefetch crosses segment boundary).
// ---------------------------------------------------------------------------
__global__ __launch_bounds__(256)
void gemm_gateB(const unsigned short* __restrict__ Tcat,
                const unsigned short* __restrict__ Wcat,
                const float* __restrict__ cell,
                float* __restrict__ out_c, float* __restrict__ out_h,
                unsigned short* __restrict__ CbT)
{
    __shared__ alignas(16) unsigned short lds[32768];   // 2 x (A8192|B8192), reused as ldsT

    const int tid = threadIdx.x;
    const int lane = tid & 63;
    const int w = tid >> 6;
    const int zc = (blockIdx.z == 0);

    int orig = blockIdx.x + 4 * blockIdx.y;              // 0..511 per z-slice
    int swz = (orig & 7) * 64 + (orig >> 3);             // XCD chunk swizzle
    const int x = swz & 3;
    const int b = swz >> 2;
    const int tm = (x >> 1) * 128;
    const int tn = (x & 1) * 128;
    const int wm = (w >> 1) * 64;
    const int wn = (w & 1) * 64;

    const int nseg = zc ? 3 : 1;
    auto abase = [&](int seg) -> const unsigned short* {
        int gv = zc ? (seg + (seg >> 1)) : 2;            // {0,1,3} or {2}
        return Tcat + (long)gv * 16777216 + (long)b * 131072 + (long)tm * 512;
    };
    auto bbase = [&](int seg) -> const unsigned short* {
        int gv = zc ? (seg + (seg >> 1)) : 2;
        return Wcat + (long)gv * 131072 + (long)tn * 512;
    };

    f32x4 accc[4][4];
#pragma unroll
    for (int m = 0; m < 4; ++m)
#pragma unroll
        for (int n = 0; n < 4; ++n)
            accc[m][n] = (f32x4){0.f, 0.f, 0.f, 0.f};

    stage_tile(abase(0), 512, bbase(0), 512, lds, 0, tid);
    __syncthreads();
    int cur = 0;
    const int nt = nseg * 8;
    for (int seg = 0; seg < nseg; ++seg) {
        f32x4 acc[4][4];
#pragma unroll
        for (int m = 0; m < 4; ++m)
#pragma unroll
            for (int n = 0; n < 4; ++n)
                acc[m][n] = (f32x4){0.f, 0.f, 0.f, 0.f};
        for (int ks = 0; ks < 8; ++ks) {
            int u = seg * 8 + ks;
            if (u + 1 < nt) {
                int s2 = (u + 1) >> 3;
                int k2 = ((u + 1) & 7) * 64;
                stage_tile(abase(s2), 512, bbase(s2), 512, lds + (cur ^ 1) * 16384, k2, tid);
            }
            compute_tile(lds + cur * 16384, lane, wm, wn, acc);
            __syncthreads();
            cur ^= 1;
        }
#pragma unroll
        for (int m = 0; m < 4; ++m)
#pragma unroll
            for (int n = 0; n < 4; ++n)
#pragma unroll
                for (int r = 0; r < 4; ++r) {
                    float v = acc[m][n][r];
                    accc[m][n][r] += (v > 0.f ? v : 0.f);
                }
    }

    const int r0 = (lane >> 4) * 4;
    const int c0 = lane & 15;
    if (zc) {
        unsigned short (*ldsT)[136] = (unsigned short(*)[136])lds;
        const float* cb = cell + (long)b * 65536;
        float* co = out_c + (long)b * 65536;
#pragma unroll
        for (int m = 0; m < 4; ++m)
#pragma unroll
            for (int n = 0; n < 4; ++n)
#pragma unroll
                for (int r = 0; r < 4; ++r) {
                    int row = wm + m * 16 + r0 + r;   // local 0..127
                    int col = wn + n * 16 + c0;       // local 0..127
                    float v = accc[m][n][r] + cb[(long)(tm + row) * 256 + tn + col];
                    co[(long)(tm + row) * 256 + tn + col] = v;
                    ldsT[col][row] = f2bf(v);
                }
        __syncthreads();
        unsigned short* cbt = CbT + (long)b * 65536;
#pragma unroll
        for (int it = 0; it < 8; ++it) {
            int idx = it * 256 + tid;      // 0..2047
            int jj = idx >> 4;             // local j (= col) 0..127
            int ch = idx & 15;             // 16 chunks of 8 el
            uint4 v = *(const uint4*)&ldsT[jj][ch * 8];
            *(uint4*)&cbt[(long)(tn + jj) * 256 + tm + ch * 8] = v;
        }
    } else {
        float* ho = out_h + (long)b * 65536;
#pragma unroll
        for (int m = 0; m < 4; ++m)
#pragma unroll
            for (int n = 0; n < 4; ++n)
#pragma unroll
                for (int r = 0; r < 4; ++r) {
                    int row = tm + wm + m * 16 + r0 + r;
                    int col = tn + wn + n * 16 + c0;
                    ho[(long)row * 256 + col] = accc[m][n][r];
                }
    }
}

// ---------------------------------------------------------------------------
// Generic NT GEMM (M=N=256 per batch), dbuf + swizzle. MODE 0: bf16 raw store;
// MODE 2: f32 += relu.
// ---------------------------------------------------------------------------
template <int MODE>
__global__ __launch_bounds__(256)
void gemm_nt2(const unsigned short* __restrict__ A, int lda, long sAy,
              const unsigned short* __restrict__ B, int ldb, long sBy,
              void* __restrict__ Cv, int ldc, long sCy, int nt)
{
    __shared__ alignas(16) unsigned short lds[32768];

    const int tid = threadIdx.x;
    const int lane = tid & 63;
    const int w = tid >> 6;

    int orig = blockIdx.x + 4 * blockIdx.y;
    int swz = (orig & 7) * 64 + (orig >> 3);
    const int x = swz & 3;
    const int b = swz >> 2;
    const int tm = (x >> 1) * 128;
    const int tn = (x & 1) * 128;
    const int wm = (w >> 1) * 64;
    const int wn = (w & 1) * 64;

    const unsigned short* Ap = A + b * sAy + (long)tm * lda;
    const unsigned short* Bp = B + b * sBy + (long)tn * ldb;

    f32x4 acc[4][4];
#pragma unroll
    for (int m = 0; m < 4; ++m)
#pragma unroll
        for (int n = 0; n < 4; ++n)
            acc[m][n] = (f32x4){0.f, 0.f, 0.f, 0.f};

    stage_tile(Ap, lda, Bp, ldb, lds, 0, tid);
    __syncthreads();
    int cur = 0;
    for (int t = 0; t < nt; ++t) {
        if (t + 1 < nt)
            stage_tile(Ap, lda, Bp, ldb, lds + (cur ^ 1) * 16384, (t + 1) * 64, tid);
        compute_tile(lds + cur * 16384, lane, wm, wn, acc);
        __syncthreads();
        cur ^= 1;
    }

    const long coff = b * sCy;
    const int r0 = (lane >> 4) * 4;
    const int c0 = lane & 15;

    if (MODE == 0) {
        unsigned short* C = (unsigned short*)Cv + coff;
#pragma unroll
        for (int m = 0; m < 4; ++m)
#pragma unroll
            for (int n = 0; n < 4; ++n)
#pragma unroll
                for (int r = 0; r < 4; ++r) {
                    int row = tm + wm + m * 16 + r0 + r;
                    int col = tn + wn + n * 16 + c0;
                    C[(long)row * ldc + col] = f2bf(acc[m][n][r]);
                }
    } else {
        float* C = (float*)Cv + coff;
#pragma unroll
        for (int m = 0; m < 4; ++m)
#pragma unroll
            for (int n = 0; n < 4; ++n)
#pragma unroll
                for (int r = 0; r < 4; ++r) {
                    int row = tm + wm + m * 16 + r0 + r;
                    int col = tn + wn + n * 16 + c0;
                    long idx = (long)row * ldc + col;
                    float v = acc[m][n][r];
                    C[idx] += (v > 0.f ? v : 0.f);
                }
    }
}

// ---------------------------------------------------------------------------
extern "C" void kernel_launch(void* const* d_in, const int* in_sizes, int n_in,
                              void* d_out, int out_size, void* d_ws, size_t ws_size,
                              hipStream_t stream)
{
    (void)in_sizes; (void)n_in; (void)out_size; (void)ws_size;

    const float* X    = (const float*)d_in[0];
    const float* H    = (const float*)d_in[1];
    const float* cell = (const float*)d_in[2];
    const float* Wxp[4] = {(const float*)d_in[3], (const float*)d_in[4],
                           (const float*)d_in[5], (const float*)d_in[6]};
    const float* Whp[4] = {(const float*)d_in[7], (const float*)d_in[8],
                           (const float*)d_in[9], (const float*)d_in[10]};
    const float* Wocf = (const float*)d_in[11];

    float* out_h = (float*)d_out;                  // [128][256][256]
    float* out_c = out_h + 8388608;                // [128][256][256]

    unsigned short* ws   = (unsigned short*)d_ws;  // bf16 elements (ws = 256 MiB)
    unsigned short* XbT  = ws;                     //  8,388,608 el
    unsigned short* HbT  = ws + 8388608;           //  8,388,608 el
    unsigned short* Wcat = ws + 16777216;          //    524,288 el [4][256][512]
    unsigned short* Wocb = ws + 17301504;          //     65,536 el
    unsigned short* Tcat = ws + 17367040;          // 67,108,864 el [4][128][256][512]
    unsigned short* CbT  = XbT;                    // reuse (dead after stage A)
    unsigned short* U    = HbT;                    // reuse (dead after stage A)

    // 1. X^T, H^T -> bf16
    transpose_cvt<<<dim3(16, 128, 2), 256, 0, stream>>>(X, XbT, H, HbT);
    // 2. weights -> bf16
    cvt_weights<<<dim3(2304), 256, 0, stream>>>(Wxp[0], Wxp[1], Wxp[2], Wxp[3],
                                                Whp[0], Whp[1], Whp[2], Whp[3],
                                                Wocf, Wcat, Wocb);
    // 3. stage A for all 4 gates
    gemm_stageA<<<dim3(4, 128, 8), 256, 0, stream>>>(Wcat, XbT, HbT, Tcat);
    // 4. stage B fused: z=0 -> c (+CbT), z=1 -> o -> out_h
    gemm_gateB<<<dim3(4, 128, 2), 256, 0, stream>>>(Tcat, Wcat, cell, out_c, out_h, CbT);
    // 5. U[b][o][j] = sum_i Woc[o,i] * c^T[b][j][i]   (bf16 out)
    gemm_nt2<0><<<dim3(4, 128), 256, 0, stream>>>(
        Wocb, 256, 0L, CbT, 256, 65536L,
        (void*)U, 256, 65536L, 4);
    // 6. h = ogate + relu(U . Woc^T)   (fp32 RMW on out_h)
    gemm_nt2<2><<<dim3(4, 128), 256, 0, stream>>>(
        U, 256, 65536L, Wocb, 256, 0L,
        (void*)out_h, 256, 65536L, 4);
}